// Round 4
// baseline (150.519 us; speedup 1.0000x reference)
//
#include <hip/hip_runtime.h>

#define B_   16
#define S_   128
#define R_   1024
#define KIN  25
#define H_   128
#define MID  256
#define KP   160    // weight K stride (padded to 5x32)
#define KL   168    // LDS inter row stride (84 dw % 32 = 20 -> bank spread)
#define ROWS 16     // rows per block

typedef _Float16 half8  __attribute__((ext_vector_type(8)));
typedef __fp16   h16x4  __attribute__((ext_vector_type(4)));
typedef __fp16   h16x2  __attribute__((ext_vector_type(2)));
typedef float    f32x4  __attribute__((ext_vector_type(4)));

// inter k-order: [h(0..127) | x(128..152) | c(153) | pad]
__device__ __forceinline__ int orig_k(int kp) {
    if (kp < H_)        return KIN + kp;
    if (kp < H_ + KIN)  return kp - H_;
    if (kp == H_ + KIN) return H_ + KIN;
    return -1;
}

// ---------------------------------------------------------------------------
// prep (coalesced): block kp<KP computes WTP[:,kp] (Wh2 reads coalesced over
// threads, Wh1[ok][m] uniform-broadcast). block kp==KP computes woP.
// ---------------------------------------------------------------------------
__global__ void prep_kernel(const float* __restrict__ Wo1, const float* __restrict__ Wo2,
                            const float* __restrict__ Wh1, const float* __restrict__ Wh2,
                            _Float16* __restrict__ WTP, _Float16* __restrict__ woP)
{
    const int kp = blockIdx.x;
    const int t  = threadIdx.x;            // 128 threads
    if (kp < KP) {
        const int ok = orig_k(kp);
        float acc = 0.f;
        if (ok >= 0) {
            const float* w1 = Wh1 + (long)ok * MID;
            for (int m = 0; m < MID; ++m)
                acc += w1[m] * Wh2[m * H_ + t];
        }
        WTP[t * KP + kp] = (_Float16)acc;
    } else {
#pragma unroll
        for (int r = 0; r < 2; ++r) {
            int k2 = t + r * 128;
            if (k2 < KP) {
                int ok = orig_k(k2);
                float acc = 0.f;
                if (ok >= 0)
                    for (int m = 0; m < MID; ++m)
                        acc += Wo1[ok * MID + m] * Wo2[m];
                woP[k2] = (_Float16)acc;
            }
        }
    }
}

// ---------------------------------------------------------------------------
// main: 1024 blocks x 256 thr (4 blocks/CU, 16 waves/CU). Block owns 16 rows.
// Swapped MFMA: D = WcT(A-op, regs) @ interT(B-op, LDS). wave = h-quarter.
// x prefetched 2 steps ahead (manual 2x unroll, named reg sets).
// ---------------------------------------------------------------------------
__global__ __launch_bounds__(256, 4) void rnn_main(
    const float* __restrict__ x, const float* __restrict__ hidden,
    const float* __restrict__ cost, const _Float16* __restrict__ WTP,
    const _Float16* __restrict__ woP, float* __restrict__ outs,
    float* __restrict__ hfin)
{
    __shared__ _Float16 A[2][ROWS][KL];   // 10,752 B
    __shared__ _Float16 wo_s[KP];

    const int t    = threadIdx.x;
    const int lane = t & 63, wave = t >> 6;
    const int l15  = lane & 15, lg = lane >> 4;
    const int wi   = wave;                 // h-quarter (32 cols)
    const int b    = blockIdx.x >> 6;
    const int r0   = (blockIdx.x & 63) << 4;
    const int xrow = t >> 4, xseg = t & 15;

    // ---- weights into registers (A-operand: lane l15 = weight out-row) ----
    half8 af[2][5];
#pragma unroll
    for (int it = 0; it < 2; ++it)
#pragma unroll
        for (int kb = 0; kb < 5; ++kb)
            af[it][kb] = *reinterpret_cast<const half8*>(
                &WTP[(wi * 32 + it * 16 + l15) * KP + kb * 32 + lg * 8]);

    if (t < KP / 8)
        reinterpret_cast<half8*>(wo_s)[t] = reinterpret_cast<const half8*>(woP)[t];

    half8 wz;
#pragma unroll
    for (int u = 0; u < 8; ++u) wz[u] = (_Float16)0.f;

    // ---- init LDS buffer 0 ----
    if (t < ROWS) {
#pragma unroll
        for (int k = H_ + KIN + 1; k < KL; ++k) {
            A[0][t][k] = (_Float16)0.f;
            A[1][t][k] = (_Float16)0.f;
        }
    }
    {   // h(0): row = t>>4, 8 cols at (t&15)*8
        const float4* h4 = reinterpret_cast<const float4*>(
            hidden + ((long)(b * R_ + r0 + xrow)) * H_ + (t & 15) * 8);
        float4 p0 = h4[0], p1 = h4[1];
        h16x2 c0 = __builtin_amdgcn_cvt_pkrtz(p0.x, p0.y);
        h16x2 c1 = __builtin_amdgcn_cvt_pkrtz(p0.z, p0.w);
        h16x2 c2 = __builtin_amdgcn_cvt_pkrtz(p1.x, p1.y);
        h16x2 c3 = __builtin_amdgcn_cvt_pkrtz(p1.z, p1.w);
        h16x4 v0; v0[0]=c0[0]; v0[1]=c0[1]; v0[2]=c1[0]; v0[3]=c1[1];
        h16x4 v1; v1[0]=c2[0]; v1[1]=c2[1]; v1[2]=c3[0]; v1[3]=c3[1];
        *reinterpret_cast<h16x4*>(&A[0][xrow][(t & 15) * 8])     = v0;
        *reinterpret_cast<h16x4*>(&A[0][xrow][(t & 15) * 8 + 4]) = v1;
    }
    {   // x(0), c(0)
        const float* xs = x + (((long)(b * S_)) * R_ + r0 + xrow) * KIN;
        if (xseg < 6) {
            h16x2 ca = __builtin_amdgcn_cvt_pkrtz(xs[xseg*4],   xs[xseg*4+1]);
            h16x2 cb = __builtin_amdgcn_cvt_pkrtz(xs[xseg*4+2], xs[xseg*4+3]);
            h16x4 v; v[0]=ca[0]; v[1]=ca[1]; v[2]=cb[0]; v[3]=cb[1];
            *reinterpret_cast<h16x4*>(&A[0][xrow][H_ + xseg * 4]) = v;
        } else if (xseg == 6) {
            h16x2 ca = __builtin_amdgcn_cvt_pkrtz(xs[24], cost[b * S_]);
            *reinterpret_cast<h16x2*>(&A[0][xrow][H_ + 24]) = ca;
        }
    }
    __syncthreads();

    const f32x4 fz = {0.f, 0.f, 0.f, 0.f};
    f32x4 acc[2];

    auto load_x = [&](int s, float& v0, float& v1, float& v2, float& v3, float& vc) {
        v0 = v1 = v2 = v3 = vc = 0.f;
        if (s < S_) {
            const float* xs = x + (((long)(b * S_ + s)) * R_ + r0 + xrow) * KIN;
            if (xseg < 6) {
                v0 = xs[xseg*4];   v1 = xs[xseg*4+1];
                v2 = xs[xseg*4+2]; v3 = xs[xseg*4+3];
            } else if (xseg == 6) {
                v0 = xs[24];
                vc = cost[b * S_ + s];
            }
        }
    };

    auto step = [&](int s, float px0, float px1, float px2, float px3, float pxc,
                    float& q0, float& q1, float& q2, float& q3, float& qc) {
        const int cur = s & 1, nxt = cur ^ 1;
        load_x(s + 2, q0, q1, q2, q3, qc);   // issue early, consumed next step

        acc[0] = fz; acc[1] = fz;
        f32x4 acc_o = fz;
#pragma unroll
        for (int kb = 0; kb < 5; ++kb) {
            half8 bf = *reinterpret_cast<const half8*>(
                &A[cur][l15][kb * 32 + lg * 8]);
            acc[0] = __builtin_amdgcn_mfma_f32_16x16x32_f16(af[0][kb], bf, acc[0], 0, 0, 0);
            acc[1] = __builtin_amdgcn_mfma_f32_16x16x32_f16(af[1][kb], bf, acc[1], 0, 0, 0);
            if (wi == 0) {
                half8 wv = (l15 == 0)
                    ? *reinterpret_cast<const half8*>(&wo_s[kb * 32 + lg * 8]) : wz;
                acc_o = __builtin_amdgcn_mfma_f32_16x16x32_f16(wv, bf, acc_o, 0, 0, 0);
            }
        }

        if (wi == 0 && lg == 0)
            outs[((long)(b * S_ + s)) * R_ + r0 + l15] = acc_o[0];

        if (s + 1 < S_) {
#pragma unroll
            for (int it = 0; it < 2; ++it) {
                h16x2 lo = __builtin_amdgcn_cvt_pkrtz(acc[it][0], acc[it][1]);
                h16x2 hi = __builtin_amdgcn_cvt_pkrtz(acc[it][2], acc[it][3]);
                h16x4 v; v[0]=lo[0]; v[1]=lo[1]; v[2]=hi[0]; v[3]=hi[1];
                *reinterpret_cast<h16x4*>(
                    &A[nxt][l15][wi * 32 + it * 16 + lg * 4]) = v;
            }
            if (xseg < 6) {
                h16x2 ca = __builtin_amdgcn_cvt_pkrtz(px0, px1);
                h16x2 cb = __builtin_amdgcn_cvt_pkrtz(px2, px3);
                h16x4 v; v[0]=ca[0]; v[1]=ca[1]; v[2]=cb[0]; v[3]=cb[1];
                *reinterpret_cast<h16x4*>(&A[nxt][xrow][H_ + xseg * 4]) = v;
            } else if (xseg == 6) {
                h16x2 ca = __builtin_amdgcn_cvt_pkrtz(px0, pxc);
                *reinterpret_cast<h16x2*>(&A[nxt][xrow][H_ + 24]) = ca;
            }
        }
        __syncthreads();
    };

    float a0, a1, a2, a3, ac;
    float b0, b1, b2, b3, bc;
    load_x(1, a0, a1, a2, a3, ac);           // x(1): consumed at end of step 0

    for (int s = 0; s < S_; s += 2) {        // S_ even: named-set ping-pong
        step(s,     a0, a1, a2, a3, ac,  b0, b1, b2, b3, bc);
        step(s + 1, b0, b1, b2, b3, bc,  a0, a1, a2, a3, ac);
    }

    // h_final from fp32 accumulators of last step
#pragma unroll
    for (int it = 0; it < 2; ++it) {
        *reinterpret_cast<f32x4*>(
            &hfin[((long)(b * R_ + r0 + l15)) * H_ + wi * 32 + it * 16 + lg * 4])
            = acc[it];
    }
}

// ---------------------------------------------------------------------------
extern "C" void kernel_launch(void* const* d_in, const int* in_sizes, int n_in,
                              void* d_out, int out_size, void* d_ws, size_t ws_size,
                              hipStream_t stream)
{
    const float* x      = (const float*)d_in[0];
    const float* hidden = (const float*)d_in[1];
    const float* cost   = (const float*)d_in[2];
    const float* Wo1    = (const float*)d_in[3];
    const float* Wo2    = (const float*)d_in[4];
    const float* Wh1    = (const float*)d_in[5];
    const float* Wh2    = (const float*)d_in[6];

    float* outs = (float*)d_out;                    // [B,S,R]
    float* hfin = outs + (long)B_ * S_ * R_;        // [B,R,H]

    _Float16* WTP = (_Float16*)d_ws;                // [128][160]
    _Float16* woP = WTP + (size_t)H_ * KP;          // [160]

    prep_kernel<<<KP + 1, 128, 0, stream>>>(Wo1, Wo2, Wh1, Wh2, WTP, woP);
    rnn_main<<<1024, 256, 0, stream>>>(x, hidden, cost, WTP, woP, outs, hfin);
}

// Round 5
// 140.478 us; speedup vs baseline: 1.0715x; 1.0715x over previous
//
#include <hip/hip_runtime.h>

#define B_   16
#define S_   128
#define R_   1024
#define KIN  25
#define H_   128
#define MID  256
#define KP   160    // weight K stride (10 blocks of 16)
#define KLH  132    // A row stride (halves): 66 dw == 2 mod 4 -> b64-aligned, 2-way banks (free)
#define XA   36     // x-arena row stride (18 dw == 2 mod 4)
#define ROWS 32     // rows per block (= 32x32 MFMA N dim)

typedef _Float16 h8  __attribute__((ext_vector_type(8)));
typedef _Float16 h4  __attribute__((ext_vector_type(4)));
typedef _Float16 h2  __attribute__((ext_vector_type(2)));
typedef float    f16v __attribute__((ext_vector_type(16)));
typedef float    f4v  __attribute__((ext_vector_type(4)));

__device__ __forceinline__ h2 pk2(float a, float b) {
    auto r = __builtin_amdgcn_cvt_pkrtz(a, b);
    h2 o; o[0] = (_Float16)r[0]; o[1] = (_Float16)r[1]; return o;
}

// inter k-order: [h(0..127) | x(128..152) | c(153) | pad(154..159)]
__device__ __forceinline__ int orig_k(int kp) {
    if (kp < H_)        return KIN + kp;
    if (kp < H_ + KIN)  return kp - H_;
    if (kp == H_ + KIN) return H_ + KIN;
    return -1;
}

// ---------------------------------------------------------------------------
__global__ void prep_kernel(const float* __restrict__ Wo1, const float* __restrict__ Wo2,
                            const float* __restrict__ Wh1, const float* __restrict__ Wh2,
                            _Float16* __restrict__ WTP, _Float16* __restrict__ woP)
{
    const int kp = blockIdx.x;
    const int t  = threadIdx.x;            // 128 threads
    if (kp < KP) {
        const int ok = orig_k(kp);
        float acc = 0.f;
        if (ok >= 0) {
            const float* w1 = Wh1 + (long)ok * MID;
            for (int m = 0; m < MID; ++m)
                acc += w1[m] * Wh2[m * H_ + t];
        }
        WTP[t * KP + kp] = (_Float16)acc;
    } else {
#pragma unroll
        for (int r = 0; r < 2; ++r) {
            int k2 = t + r * 128;
            if (k2 < KP) {
                int ok = orig_k(k2);
                float acc = 0.f;
                if (ok >= 0)
                    for (int m = 0; m < MID; ++m)
                        acc += Wo1[ok * MID + m] * Wo2[m];
                woP[k2] = (_Float16)acc;
            }
        }
    }
}

// ---------------------------------------------------------------------------
// 512 blocks x 256 thr (2 blocks/CU, 8 waves/CU). Block owns 32 rows.
// mfma_f32_32x32x16_f16 swapped: D = Wc-frag(A, regs) @ inter^T-frag(B, LDS).
// Wave wi owns one 32-col i-tile. Steady step: no global memory ops at all.
// ---------------------------------------------------------------------------
__global__ __launch_bounds__(256, 2) void rnn_main(
    const float* __restrict__ x, const float* __restrict__ hidden,
    const float* __restrict__ cost, const _Float16* __restrict__ WTP,
    const _Float16* __restrict__ woP, float* __restrict__ outs,
    float* __restrict__ hfin)
{
    __shared__ _Float16 A[2][ROWS][KLH];        // 16,896 B (h only, cols 0..127)
    __shared__ _Float16 xar[2][4][ROWS][XA];    // 18,432 B (x+c fp16, dbl-buffered)

    const int t    = threadIdx.x;
    const int lane = t & 63, wave = t >> 6;
    const int n    = lane & 31, hi = lane >> 5;
    const int wi   = wave;                      // 32-col i-tile
    const int b    = blockIdx.x >> 5;
    const int r0   = (blockIdx.x & 31) << 5;

    // ---- weights into registers ----
    // A-frag: lane holds W[m = wi*32+n][k = kb*16 + hi*8 + u]
    h8 af[10], wof[10];
#pragma unroll
    for (int kb = 0; kb < 10; ++kb) {
        af[kb]  = *reinterpret_cast<const h8*>(&WTP[(wi * 32 + n) * KP + kb * 16 + hi * 8]);
        wof[kb] = *reinterpret_cast<const h8*>(&woP[kb * 16 + hi * 8]);
    }

    // ---- zero arena pad cols 26..35 (written once; x overwrites only 0..25) ----
    for (int z = t; z < 2 * 4 * ROWS; z += 256) {
        _Float16* row = &xar[z >> 7][(z >> 5) & 3][z & 31][0];
#pragma unroll
        for (int c = 26; c < XA; ++c) row[c] = (_Float16)0.f;
    }

    // ---- h(0) -> A[0] ----
    {
        int row = t >> 3, seg = t & 7;
        const float4* hp = reinterpret_cast<const float4*>(
            hidden + ((long)(b * R_ + r0 + row)) * H_ + seg * 16);
#pragma unroll
        for (int q2 = 0; q2 < 2; ++q2) {
            float4 p0 = hp[q2 * 2], p1 = hp[q2 * 2 + 1];
            h2 a0 = pk2(p0.x, p0.y), a1 = pk2(p0.z, p0.w);
            h2 a2 = pk2(p1.x, p1.y), a3 = pk2(p1.z, p1.w);
            h4 v0; v0[0] = a0[0]; v0[1] = a0[1]; v0[2] = a1[0]; v0[3] = a1[1];
            h4 v1; v1[0] = a2[0]; v1[1] = a2[1]; v1[2] = a3[0]; v1[3] = a3[1];
            *reinterpret_cast<h4*>(&A[0][row][seg * 16 + q2 * 8])     = v0;
            *reinterpret_cast<h4*>(&A[0][row][seg * 16 + q2 * 8 + 4]) = v1;
        }
    }

    // ---- x batch: 256 thr cover 4 steps x 32 rows (2 thr/row) ----
    const int job = t >> 1, jst = job >> 5, jrow = job & 31, jh = t & 1;
    float xb[13]; float cb = 0.f;

    auto xload = [&](int s0) {      // issue loads for steps s0..s0+3
        if (s0 < S_) {
            const float* p = x + ((long)(b * S_ + s0 + jst) * R_ + r0 + jrow) * KIN + jh * 12;
#pragma unroll
            for (int i = 0; i < 12; ++i) xb[i] = p[i];
            if (jh) { xb[12] = p[12]; cb = cost[b * S_ + s0 + jst]; }
        }
    };
    auto xcvt = [&](int slot) {     // convert reg batch -> arena[slot]
        _Float16* dst = &xar[slot][jst][jrow][jh * 12];
#pragma unroll
        for (int g = 0; g < 3; ++g) {
            h2 a0 = pk2(xb[g * 4 + 0], xb[g * 4 + 1]);
            h2 a1 = pk2(xb[g * 4 + 2], xb[g * 4 + 3]);
            h4 v; v[0] = a0[0]; v[1] = a0[1]; v[2] = a1[0]; v[3] = a1[1];
            *reinterpret_cast<h4*>(&dst[g * 4]) = v;
        }
        if (jh) {
            h2 tail = pk2(xb[12], cb);   // x[24], c at cols 24,25
            *reinterpret_cast<h2*>(&xar[slot][jst][jrow][24]) = tail;
        }
    };

    xload(0);
    xcvt(0);        // superstep 0 -> arena slot 0
    xload(4);       // batch for superstep 1 (held in regs)
    __syncthreads();

    f16v acc_e, acc_o;
#pragma unroll
    for (int i = 0; i < 16; ++i) { acc_e[i] = 0.f; acc_o[i] = 0.f; }
    float og[4];

    for (int s4 = 0; s4 < S_; s4 += 4) {
        {   // superstep boundary: cvt next batch, prefetch batch after
            int q = s4 >> 2;
            if (s4 + 4 < S_) xcvt((q + 1) & 1);
            xload(s4 + 8);
        }
        const int slot = (s4 >> 2) & 1;
#pragma unroll
        for (int j = 0; j < 4; ++j) {
            const int s = s4 + j;
            const int cur = j & 1, nxt = cur ^ 1;
#pragma unroll
            for (int i = 0; i < 16; ++i) { acc_e[i] = 0.f; acc_o[i] = 0.f; }
            h2 po; po[0] = (_Float16)0.f; po[1] = (_Float16)0.f;

#pragma unroll
            for (int kb = 0; kb < 10; ++kb) {
                h4 lo4, hv4;
                if (kb < 8) {
                    const _Float16* pr = &A[cur][n][kb * 16 + hi * 8];
                    lo4 = *reinterpret_cast<const h4*>(pr);
                    hv4 = *reinterpret_cast<const h4*>(pr + 4);
                } else {
                    const _Float16* pr = &xar[slot][j][n][(kb - 8) * 16 + hi * 8];
                    lo4 = *reinterpret_cast<const h4*>(pr);
                    hv4 = *reinterpret_cast<const h4*>(pr + 4);
                }
                h8 bf;
                bf[0] = lo4[0]; bf[1] = lo4[1]; bf[2] = lo4[2]; bf[3] = lo4[3];
                bf[4] = hv4[0]; bf[5] = hv4[1]; bf[6] = hv4[2]; bf[7] = hv4[3];

                if (kb & 1) acc_o = __builtin_amdgcn_mfma_f32_32x32x16_f16(af[kb], bf, acc_o, 0, 0, 0);
                else        acc_e = __builtin_amdgcn_mfma_f32_32x32x16_f16(af[kb], bf, acc_e, 0, 0, 0);

                // out-dot partial (packed fp16), reuses bf: zero extra LDS reads
#pragma unroll
                for (int u = 0; u < 8; u += 2) {
                    h2 bp; bp[0] = bf[u]; bp[1] = bf[u + 1];
                    h2 wp; wp[0] = wof[kb][u]; wp[1] = wof[kb][u + 1];
                    po += bp * wp;
                }
            }

            float pof = (float)po[0] + (float)po[1];
            pof += __shfl_xor(pof, 32, 64);   // combine k-halves (hi)
            og[j] = pof;

            if (s < S_ - 1) {
                // h(s+1) -> A[nxt]: D col=n(row), D rows m=(r&3)+8*(r>>2)+4*hi
#pragma unroll
                for (int q2 = 0; q2 < 4; ++q2) {
                    float s0 = acc_e[q2 * 4 + 0] + acc_o[q2 * 4 + 0];
                    float s1 = acc_e[q2 * 4 + 1] + acc_o[q2 * 4 + 1];
                    float s2 = acc_e[q2 * 4 + 2] + acc_o[q2 * 4 + 2];
                    float s3 = acc_e[q2 * 4 + 3] + acc_o[q2 * 4 + 3];
                    h2 a0 = pk2(s0, s1), a1 = pk2(s2, s3);
                    h4 v; v[0] = a0[0]; v[1] = a0[1]; v[2] = a1[0]; v[3] = a1[1];
                    *reinterpret_cast<h4*>(&A[nxt][n][wi * 32 + q2 * 8 + hi * 4]) = v;
                }
            }
            __syncthreads();
        }
        // flush 4 outs (wave 3 only; drains at next group's first barrier)
        if (wave == 3 && lane < 32) {
#pragma unroll
            for (int j = 0; j < 4; ++j)
                outs[((long)(b * S_ + s4 + j)) * R_ + r0 + n] = og[j];
        }
    }

    // ---- h_final from step-127 accumulators (fp32) ----
#pragma unroll
    for (int q2 = 0; q2 < 4; ++q2) {
        f4v v;
        v[0] = acc_e[q2 * 4 + 0] + acc_o[q2 * 4 + 0];
        v[1] = acc_e[q2 * 4 + 1] + acc_o[q2 * 4 + 1];
        v[2] = acc_e[q2 * 4 + 2] + acc_o[q2 * 4 + 2];
        v[3] = acc_e[q2 * 4 + 3] + acc_o[q2 * 4 + 3];
        *reinterpret_cast<f4v*>(
            &hfin[((long)(b * R_ + r0 + n)) * H_ + wi * 32 + q2 * 8 + hi * 4]) = v;
    }
}

// ---------------------------------------------------------------------------
extern "C" void kernel_launch(void* const* d_in, const int* in_sizes, int n_in,
                              void* d_out, int out_size, void* d_ws, size_t ws_size,
                              hipStream_t stream)
{
    const float* x      = (const float*)d_in[0];
    const float* hidden = (const float*)d_in[1];
    const float* cost   = (const float*)d_in[2];
    const float* Wo1    = (const float*)d_in[3];
    const float* Wo2    = (const float*)d_in[4];
    const float* Wh1    = (const float*)d_in[5];
    const float* Wh2    = (const float*)d_in[6];

    float* outs = (float*)d_out;                    // [B,S,R]
    float* hfin = outs + (long)B_ * S_ * R_;        // [B,R,H]

    _Float16* WTP = (_Float16*)d_ws;                // [128][160]
    _Float16* woP = WTP + (size_t)H_ * KP;          // [160]

    prep_kernel<<<KP + 1, 128, 0, stream>>>(Wo1, Wo2, Wh1, Wh2, WTP, woP);
    rnn_main<<<512, 256, 0, stream>>>(x, hidden, cost, WTP, woP, outs, hfin);
}

// Round 6
// 122.462 us; speedup vs baseline: 1.2291x; 1.1471x over previous
//
#include <hip/hip_runtime.h>

#define B_   16
#define S_   128
#define R_   1024
#define KIN  25
#define H_   128
#define MID  256
#define KP   160    // weight K stride (10 blocks of 16)
#define KLH  132    // A row stride (halves): 66 dw -> 2-way banks (free), 8B aligned
#define XA   36     // x-arena row stride (halves)
#define ROWS 32     // rows per block (= 32x32 MFMA N dim)

typedef _Float16 h8  __attribute__((ext_vector_type(8)));
typedef _Float16 h4  __attribute__((ext_vector_type(4)));
typedef _Float16 h2  __attribute__((ext_vector_type(2)));
typedef float    f16v __attribute__((ext_vector_type(16)));
typedef float    f4v  __attribute__((ext_vector_type(4)));

__device__ __forceinline__ h2 pk2(float a, float b) {
    auto r = __builtin_amdgcn_cvt_pkrtz(a, b);
    h2 o; o[0] = (_Float16)r[0]; o[1] = (_Float16)r[1]; return o;
}

// inter k-order: [h(0..127) | x(128..152) | c(153) | pad(154..159)]
__device__ __forceinline__ int orig_k(int kp) {
    if (kp < H_)        return KIN + kp;
    if (kp < H_ + KIN)  return kp - H_;
    if (kp == H_ + KIN) return H_ + KIN;
    return -1;
}

// ---------------------------------------------------------------------------
__global__ void prep_kernel(const float* __restrict__ Wo1, const float* __restrict__ Wo2,
                            const float* __restrict__ Wh1, const float* __restrict__ Wh2,
                            _Float16* __restrict__ WTP, _Float16* __restrict__ woP)
{
    const int kp = blockIdx.x;
    const int t  = threadIdx.x;            // 128 threads
    if (kp < KP) {
        const int ok = orig_k(kp);
        float acc = 0.f;
        if (ok >= 0) {
            const float* w1 = Wh1 + (long)ok * MID;
            for (int m = 0; m < MID; ++m)
                acc += w1[m] * Wh2[m * H_ + t];
        }
        WTP[t * KP + kp] = (_Float16)acc;
    } else {
#pragma unroll
        for (int r = 0; r < 2; ++r) {
            int k2 = t + r * 128;
            if (k2 < KP) {
                int ok = orig_k(k2);
                float acc = 0.f;
                if (ok >= 0)
                    for (int m = 0; m < MID; ++m)
                        acc += Wo1[ok * MID + m] * Wo2[m];
                woP[k2] = (_Float16)acc;
            }
        }
    }
}

// ---------------------------------------------------------------------------
// 512 blocks x 128 thr (2 blocks/CU, 2 waves/block). Block owns 32 rows.
// Wave owns 2 i-tiles (64 h-dims): 20 MFMA/step. Steady step: LDS only.
// Raw s_barrier (lgkmcnt-only) -> x prefetch never drained in-loop.
// ---------------------------------------------------------------------------
__global__ __launch_bounds__(128, 1) void rnn_main(
    const float* __restrict__ x, const float* __restrict__ hidden,
    const float* __restrict__ cost, const _Float16* __restrict__ WTP,
    const _Float16* __restrict__ woP, float* __restrict__ outs,
    float* __restrict__ hfin)
{
    __shared__ _Float16 A[2][ROWS][KLH];        // 16,896 B (h cols 0..127)
    __shared__ _Float16 xar[2][4][ROWS][XA];    // 18,432 B (x+c, dbl-buffered)

    const int t    = threadIdx.x;
    const int lane = t & 63, wave = t >> 6;      // wave 0,1
    const int n    = lane & 31, hi = lane >> 5;
    const int b    = blockIdx.x >> 5;
    const int r0   = (blockIdx.x & 31) << 5;

    // ---- weights into registers ----
    // af[tile][kb]: lane holds W[m = wave*64 + tile*32 + n][k = kb*16 + hi*8 + u]
    h8 af[2][10], wof[10];
#pragma unroll
    for (int tile = 0; tile < 2; ++tile)
#pragma unroll
        for (int kb = 0; kb < 10; ++kb)
            af[tile][kb] = *reinterpret_cast<const h8*>(
                &WTP[(wave * 64 + tile * 32 + n) * KP + kb * 16 + hi * 8]);
#pragma unroll
    for (int kb = 0; kb < 10; ++kb)
        wof[kb] = *reinterpret_cast<const h8*>(&woP[kb * 16 + hi * 8]);

    // ---- zero xar pad cols 26..35 (never overwritten) ----
    for (int z = t; z < 2 * 4 * ROWS; z += 128) {
        _Float16* row = &xar[z >> 7][(z >> 5) & 3][z & 31][0];
#pragma unroll
        for (int c = 26; c < XA; ++c) row[c] = (_Float16)0.f;
    }

    // ---- h(0) -> A[0]: thread = (row t&31, 32-col seg t>>5) ----
    {
        int row = t & 31, seg = t >> 5;
        const float4* hp = reinterpret_cast<const float4*>(
            hidden + ((long)(b * R_ + r0 + row)) * H_ + seg * 32);
#pragma unroll
        for (int g = 0; g < 4; ++g) {
            float4 p0 = hp[g * 2], p1 = hp[g * 2 + 1];
            h2 a0 = pk2(p0.x, p0.y), a1 = pk2(p0.z, p0.w);
            h2 a2 = pk2(p1.x, p1.y), a3 = pk2(p1.z, p1.w);
            h4 v0; v0[0] = a0[0]; v0[1] = a0[1]; v0[2] = a1[0]; v0[3] = a1[1];
            h4 v1; v1[0] = a2[0]; v1[1] = a2[1]; v1[2] = a3[0]; v1[3] = a3[1];
            *reinterpret_cast<h4*>(&A[0][row][seg * 32 + g * 8])     = v0;
            *reinterpret_cast<h4*>(&A[0][row][seg * 32 + g * 8 + 4]) = v1;
        }
    }

    // ---- x batching: thread = (step jst = t>>5, row jrow = t&31) ----
    const int jst = t >> 5, jrow = t & 31;
    float xb[25]; float cb = 0.f;

    auto xload = [&](int s0) {
        if (s0 < S_) {
            const float* p = x + ((long)(b * S_ + s0 + jst) * R_ + r0 + jrow) * KIN;
#pragma unroll
            for (int g = 0; g < 6; ++g) {
                float4 v = *reinterpret_cast<const float4*>(p + g * 4);
                xb[g * 4 + 0] = v.x; xb[g * 4 + 1] = v.y;
                xb[g * 4 + 2] = v.z; xb[g * 4 + 3] = v.w;
            }
            xb[24] = p[24];
            cb = cost[b * S_ + s0 + jst];
        }
    };
    auto xcvt = [&](int slot) {
        _Float16* dst = &xar[slot][jst][jrow][0];
#pragma unroll
        for (int g = 0; g < 6; ++g) {
            h2 a0 = pk2(xb[g * 4 + 0], xb[g * 4 + 1]);
            h2 a1 = pk2(xb[g * 4 + 2], xb[g * 4 + 3]);
            h4 v; v[0] = a0[0]; v[1] = a0[1]; v[2] = a1[0]; v[3] = a1[1];
            *reinterpret_cast<h4*>(&dst[g * 4]) = v;
        }
        h2 tail = pk2(xb[24], cb);
        *reinterpret_cast<h2*>(&dst[24]) = tail;
    };

    xload(0);
    xcvt(0);
    xload(4);
    __syncthreads();

    f16v acc[2];
#pragma unroll
    for (int tile = 0; tile < 2; ++tile)
#pragma unroll
        for (int i = 0; i < 16; ++i) acc[tile][i] = 0.f;

    for (int s4 = 0; s4 < S_; s4 += 4) {
        {   // superstep boundary: cvt next batch, prefetch batch after
            int q = s4 >> 2;
            if (s4 + 4 < S_) xcvt((q + 1) & 1);
            xload(s4 + 8);
        }
        const int slot = (s4 >> 2) & 1;
#pragma unroll
        for (int j = 0; j < 4; ++j) {
            const int s = s4 + j;
            const int cur = s & 1, nxt = cur ^ 1;
#pragma unroll
            for (int tile = 0; tile < 2; ++tile)
#pragma unroll
                for (int i = 0; i < 16; ++i) acc[tile][i] = 0.f;
            h2 po; po[0] = (_Float16)0.f; po[1] = (_Float16)0.f;

#pragma unroll
            for (int kb = 0; kb < 10; ++kb) {
                h4 lo4, hv4;
                if (kb < 8) {
                    const _Float16* pr = &A[cur][n][kb * 16 + hi * 8];
                    lo4 = *reinterpret_cast<const h4*>(pr);
                    hv4 = *reinterpret_cast<const h4*>(pr + 4);
                } else {
                    const _Float16* pr = &xar[slot][j][n][(kb - 8) * 16 + hi * 8];
                    lo4 = *reinterpret_cast<const h4*>(pr);
                    hv4 = *reinterpret_cast<const h4*>(pr + 4);
                }
                h8 bf;
                bf[0] = lo4[0]; bf[1] = lo4[1]; bf[2] = lo4[2]; bf[3] = lo4[3];
                bf[4] = hv4[0]; bf[5] = hv4[1]; bf[6] = hv4[2]; bf[7] = hv4[3];

                acc[0] = __builtin_amdgcn_mfma_f32_32x32x16_f16(af[0][kb], bf, acc[0], 0, 0, 0);
                acc[1] = __builtin_amdgcn_mfma_f32_32x32x16_f16(af[1][kb], bf, acc[1], 0, 0, 0);

                // out-dot partial (packed fp16), reuses bf
#pragma unroll
                for (int u = 0; u < 8; u += 2) {
                    h2 bp; bp[0] = bf[u];      bp[1] = bf[u + 1];
                    h2 wp; wp[0] = wof[kb][u]; wp[1] = wof[kb][u + 1];
                    po += bp * wp;
                }
            }

            float pof = (float)po[0] + (float)po[1];
            pof += __shfl_xor(pof, 32, 64);       // combine k-halves (hi)
            if (wave == 0 && hi == 0)
                outs[((long)(b * S_ + s)) * R_ + r0 + n] = pof;

            if (s < S_ - 1) {
                // h(s+1) -> A[nxt]: col=n(row), i = wave*64+tile*32+q2*8+hi*4+jj
#pragma unroll
                for (int tile = 0; tile < 2; ++tile)
#pragma unroll
                    for (int q2 = 0; q2 < 4; ++q2) {
                        h2 a0 = pk2(acc[tile][q2 * 4 + 0], acc[tile][q2 * 4 + 1]);
                        h2 a1 = pk2(acc[tile][q2 * 4 + 2], acc[tile][q2 * 4 + 3]);
                        h4 v; v[0] = a0[0]; v[1] = a0[1]; v[2] = a1[0]; v[3] = a1[1];
                        *reinterpret_cast<h4*>(
                            &A[nxt][n][wave * 64 + tile * 32 + q2 * 8 + hi * 4]) = v;
                    }
            }
            // raw barrier: LDS drain only (no vmcnt!) -> x prefetch stays in flight
            asm volatile("s_waitcnt lgkmcnt(0)" ::: "memory");
            __builtin_amdgcn_sched_barrier(0);
            __builtin_amdgcn_s_barrier();
            __builtin_amdgcn_sched_barrier(0);
        }
    }

    // ---- h_final from step-127 accumulators (fp32) ----
#pragma unroll
    for (int tile = 0; tile < 2; ++tile)
#pragma unroll
        for (int q2 = 0; q2 < 4; ++q2) {
            f4v v;
            v[0] = acc[tile][q2 * 4 + 0];
            v[1] = acc[tile][q2 * 4 + 1];
            v[2] = acc[tile][q2 * 4 + 2];
            v[3] = acc[tile][q2 * 4 + 3];
            *reinterpret_cast<f4v*>(
                &hfin[((long)(b * R_ + r0 + n)) * H_ + wave * 64 + tile * 32 + q2 * 8 + hi * 4]) = v;
        }
}

// ---------------------------------------------------------------------------
extern "C" void kernel_launch(void* const* d_in, const int* in_sizes, int n_in,
                              void* d_out, int out_size, void* d_ws, size_t ws_size,
                              hipStream_t stream)
{
    const float* x      = (const float*)d_in[0];
    const float* hidden = (const float*)d_in[1];
    const float* cost   = (const float*)d_in[2];
    const float* Wo1    = (const float*)d_in[3];
    const float* Wo2    = (const float*)d_in[4];
    const float* Wh1    = (const float*)d_in[5];
    const float* Wh2    = (const float*)d_in[6];

    float* outs = (float*)d_out;                    // [B,S,R]
    float* hfin = outs + (long)B_ * S_ * R_;        // [B,R,H]

    _Float16* WTP = (_Float16*)d_ws;                // [128][160]
    _Float16* woP = WTP + (size_t)H_ * KP;          // [160]

    prep_kernel<<<KP + 1, 128, 0, stream>>>(Wo1, Wo2, Wh1, Wh2, WTP, woP);
    rnn_main<<<512, 128, 0, stream>>>(x, hidden, cost, WTP, woP, outs, hfin);
}